// Round 5
// baseline (206.601 us; speedup 1.0000x reference)
//
#include <hip/hip_runtime.h>
#include <math.h>

// bf16 MFMA fragment types (gfx950): A/B = 8 bf16 (4 VGPR), C/D = 4 fp32
typedef __attribute__((ext_vector_type(8))) short bf16x8;
typedef __attribute__((ext_vector_type(4))) float f32x4;
typedef __attribute__((ext_vector_type(2))) unsigned int u32x2;
typedef __attribute__((ext_vector_type(4))) unsigned int u32x4;
typedef unsigned long long u64;

#define LDSTR 136            // W1^T LDS leading dim (shorts): 128 + 8 pad
#define TPW 8                // (fallback) 16-edge tiles per wave
#define NREP 128             // bucketize replicas
#define NBKT 64              // 8 src-ranges x 8 dst-ranges
#define PROJ_BLOCKS 512      // fused_prep: blocks 0..511 project, 512..639 bucket

// f32 -> bf16 round-to-nearest-even
static __device__ __forceinline__ unsigned int pack2bf(float x, float y) {
  unsigned int ux = __builtin_bit_cast(unsigned int, x);
  ux += 0x7fffu + ((ux >> 16) & 1u);
  unsigned int uy = __builtin_bit_cast(unsigned int, y);
  uy += 0x7fffu + ((uy >> 16) & 1u);
  return (ux >> 16) | (uy & 0xffff0000u);
}
static __device__ __forceinline__ unsigned short f2bf_s(float x) {
  unsigned int ux = __builtin_bit_cast(unsigned int, x);
  ux += 0x7fffu + ((ux >> 16) & 1u);
  return (unsigned short)(ux >> 16);
}
static __device__ __forceinline__ bf16x8 make_afrag(float4 lo, float4 hi) {
  u32x4 p;
  p[0] = pack2bf(lo.x, lo.y);
  p[1] = pack2bf(lo.z, lo.w);
  p[2] = pack2bf(hi.x, hi.y);
  p[3] = pack2bf(hi.z, hi.w);
  return __builtin_bit_cast(bf16x8, p);
}

// Quantize one f32 to biased uint8 given inv = 127/rowmax (0 if rowmax==0).
static __device__ __forceinline__ unsigned int q8(float v, float inv) {
  return (unsigned int)((int)rintf(v * inv) + 128);
}

// int8 edge MLP inner dot: h = relu((p-128)*sp + (q-128)*sq), acc += h*w2.
static __device__ __forceinline__ float dot8i(u32x2 P, u32x2 Q, float sp, float sq,
                                              const float* w2v) {
  const float t_ = -128.f * (sp + sq);
  float acc = 0.f;
  #pragma unroll
  for (int k2 = 0; k2 < 2; ++k2) {
    const unsigned int pd = P[k2], qd = Q[k2];
    #pragma unroll
    for (int b = 0; b < 4; ++b) {
      float pf = (float)((pd >> (8 * b)) & 0xffu);
      float qf = (float)((qd >> (8 * b)) & 0xffu);
      float h = __builtin_fmaf(pf, sp, __builtin_fmaf(qf, sq, t_));
      h = fmaxf(h, 0.f);
      acc = __builtin_fmaf(h, w2v[k2 * 4 + b], acc);
    }
  }
  return acc;
}

// ---- node_proj body: per-node projections P = emb@W1[0:64],
// Q = emb@W1[64:128] + b1, stored as INT8 rows (64 B) with per-row f32
// scales SP/SQ. Permuted channel order ch(p) = (p&3)*16 + (p>>2).
static __device__ void node_proj_body(
    const float* __restrict__ emb, const float* __restrict__ W1,
    const float* __restrict__ b1,
    unsigned int* __restrict__ P8, unsigned int* __restrict__ Q8,
    float* __restrict__ SP, float* __restrict__ SQ,
    int N, int ntiles, int nblocks, int bid)
{
  __shared__ unsigned short ls_w1t[64 * LDSTR];   // W1^T [n][k]
  const int tid  = threadIdx.x;
  const int wave = tid >> 6;
  const int lane = tid & 63;
  const int l15  = lane & 15;
  const int quad = lane >> 4;

  for (int i = tid; i < 64 * 128; i += 256) {
    int k = i >> 6, n = i & 63;                    // W1[k][n], linear read
    ls_w1t[n * LDSTR + k] = f2bf_s(W1[i]);
  }
  __syncthreads();

  float b1q[4];
  #pragma unroll
  for (int tn = 0; tn < 4; ++tn) b1q[tn] = b1[tn * 16 + l15];

  bf16x8 bfragP[4][2], bfragQ[4][2];
  #pragma unroll
  for (int tn = 0; tn < 4; ++tn)
    #pragma unroll
    for (int s = 0; s < 2; ++s) {
      bfragP[tn][s] = *(const bf16x8*)&ls_w1t[(tn * 16 + l15) * LDSTR + s * 32 + quad * 8];
      bfragQ[tn][s] = *(const bf16x8*)&ls_w1t[(tn * 16 + l15) * LDSTR + 64 + s * 32 + quad * 8];
    }

  for (int tile = bid * 4 + wave; tile < ntiles; tile += nblocks * 4) {
    const int base = tile * 16;

    bf16x8 afr0, afr1;
    {
      int node = base + l15;
      node = (node < N) ? node : N - 1;
      const float* rp = emb + (long long)node * 64 + quad * 8;
      afr0 = make_afrag(*(const float4*)(rp),      *(const float4*)(rp + 4));
      afr1 = make_afrag(*(const float4*)(rp + 32), *(const float4*)(rp + 36));
    }

    f32x4 aP[4], aQ[4];
    #pragma unroll
    for (int tn = 0; tn < 4; ++tn) { aP[tn] = (f32x4){0,0,0,0}; aQ[tn] = (f32x4){0,0,0,0}; }
    #pragma unroll
    for (int tn = 0; tn < 4; ++tn) {
      aP[tn] = __builtin_amdgcn_mfma_f32_16x16x32_bf16(afr0, bfragP[tn][0], aP[tn], 0, 0, 0);
      aQ[tn] = __builtin_amdgcn_mfma_f32_16x16x32_bf16(afr0, bfragQ[tn][0], aQ[tn], 0, 0, 0);
      aP[tn] = __builtin_amdgcn_mfma_f32_16x16x32_bf16(afr1, bfragP[tn][1], aP[tn], 0, 0, 0);
      aQ[tn] = __builtin_amdgcn_mfma_f32_16x16x32_bf16(afr1, bfragQ[tn][1], aQ[tn], 0, 0, 0);
    }

    #pragma unroll
    for (int r = 0; r < 4; ++r) {
      const int m = base + quad * 4 + r;
      float vp0 = aP[0][r], vp1 = aP[1][r], vp2 = aP[2][r], vp3 = aP[3][r];
      float vq0 = aQ[0][r] + b1q[0], vq1 = aQ[1][r] + b1q[1];
      float vq2 = aQ[2][r] + b1q[2], vq3 = aQ[3][r] + b1q[3];

      float mp = fmaxf(fmaxf(fabsf(vp0), fabsf(vp1)), fmaxf(fabsf(vp2), fabsf(vp3)));
      float mq = fmaxf(fmaxf(fabsf(vq0), fabsf(vq1)), fmaxf(fabsf(vq2), fabsf(vq3)));
      mp = fmaxf(mp, __shfl_xor(mp, 1)); mq = fmaxf(mq, __shfl_xor(mq, 1));
      mp = fmaxf(mp, __shfl_xor(mp, 2)); mq = fmaxf(mq, __shfl_xor(mq, 2));
      mp = fmaxf(mp, __shfl_xor(mp, 4)); mq = fmaxf(mq, __shfl_xor(mq, 4));
      mp = fmaxf(mp, __shfl_xor(mp, 8)); mq = fmaxf(mq, __shfl_xor(mq, 8));

      const float invP = (mp > 0.f) ? 127.f / mp : 0.f;
      const float invQ = (mq > 0.f) ? 127.f / mq : 0.f;

      if (m < N) {
        unsigned int pw = q8(vp0, invP) | (q8(vp1, invP) << 8) |
                          (q8(vp2, invP) << 16) | (q8(vp3, invP) << 24);
        unsigned int qw = q8(vq0, invQ) | (q8(vq1, invQ) << 8) |
                          (q8(vq2, invQ) << 16) | (q8(vq3, invQ) << 24);
        P8[(long long)m * 16 + l15] = pw;
        Q8[(long long)m * 16 + l15] = qw;
        if (l15 == 0) {
          SP[m] = mp * (1.f / 127.f);
          SQ[m] = mq * (1.f / 127.f);
        }
      }
    }
  }
}

// ---- bucketize body: replica r bins its contiguous edge range into 64
// (src-range, dst-range) segments. LDS cursors; 4-B entries
// (s%ndiv | (d%ndiv)<<15); posrec[e] = (bkt<<9 | pos) for the unscatter.
static __device__ void bucketize_body(
    const int* __restrict__ src, const int* __restrict__ dst,
    unsigned int* __restrict__ seg, unsigned short* __restrict__ posrec,
    unsigned int* __restrict__ cntT, int E, int ndiv, int cap, int r)
{
  __shared__ unsigned int curs[NBKT];
  const int per = (E + NREP - 1) / NREP;
  const int lo = r * per;
  const int hi = (lo + per < E) ? lo + per : E;
  for (int i = threadIdx.x; i < NBKT; i += 256) curs[i] = 0;
  __syncthreads();
  for (int e = lo + threadIdx.x; e < hi; e += 256) {
    const int s = src[e], d = dst[e];
    const int bi = s / ndiv, bj = d / ndiv;
    const int bkt = bi * 8 + bj;
    const unsigned int pos = atomicAdd(&curs[bkt], 1u);
    unsigned short pr = 0xFFFFu;
    if (pos < (unsigned)cap) {
      seg[((size_t)(r * NBKT + bkt)) * cap + pos] =
          (unsigned)(s - bi * ndiv) | ((unsigned)(d - bj * ndiv) << 15);
      pr = (unsigned short)(((unsigned)bkt << 9) | pos);
    }
    posrec[e] = pr;
  }
  __syncthreads();
  for (int bkt = threadIdx.x; bkt < NBKT; bkt += 256) {
    unsigned int c = curs[bkt];
    cntT[bkt * NREP + r] = (c < (unsigned)cap) ? c : (unsigned)cap;
  }
}

// ---- pass 0+1 fused: node_proj (blocks 0..511) and bucketize (512..639)
// are independent (disjoint reads/writes) -> run them in ONE dispatch so
// the streaming overlaps. Branch is block-uniform -> __syncthreads safe.
__global__ __launch_bounds__(256) void fused_prep(
    const float* __restrict__ emb, const float* __restrict__ W1,
    const float* __restrict__ b1,
    unsigned int* __restrict__ P8, unsigned int* __restrict__ Q8,
    float* __restrict__ SP, float* __restrict__ SQ,
    const int* __restrict__ src, const int* __restrict__ dst,
    unsigned int* __restrict__ seg, unsigned short* __restrict__ posrec,
    unsigned int* __restrict__ cntT,
    int N, int ntiles, int E, int ndiv, int cap)
{
  if (blockIdx.x < PROJ_BLOCKS)
    node_proj_body(emb, W1, b1, P8, Q8, SP, SQ, N, ntiles, PROJ_BLOCKS, blockIdx.x);
  else
    bucketize_body(src, dst, seg, posrec, cntT, E, ndiv, cap, blockIdx.x - PROJ_BLOCKS);
}

// plain node_proj (mid tier, when bucket lists don't fit ws)
__global__ __launch_bounds__(256) void node_proj(
    const float* __restrict__ emb, const float* __restrict__ W1,
    const float* __restrict__ b1,
    unsigned int* __restrict__ P8, unsigned int* __restrict__ Q8,
    float* __restrict__ SP, float* __restrict__ SQ, int N, int ntiles)
{
  node_proj_body(emb, W1, b1, P8, Q8, SP, SQ, N, ntiles, gridDim.x, blockIdx.x);
}

// ---- pass 2: bucketed edge scorer, zero-sync work assignment (R4) +
// R2-style software pipeline: next seg entry / gathers / scales issued
// BEFORE the current edge's dot, so L2-hit latency hides under compute.
// XCD k (bid%8): wave w of 1024 owns (segment r=w>>3, sub-chunk w&7) and
// walks phases j=0..7 (bucket b=k*8+j). All 8 phase counts preloaded.
__global__ __launch_bounds__(256) void edge_score_seg(
    const unsigned int* __restrict__ P8, const unsigned int* __restrict__ Q8,
    const float* __restrict__ SP, const float* __restrict__ SQ,
    const unsigned int* __restrict__ seg, const unsigned int* __restrict__ cntT,
    const float* __restrict__ W2, const float* __restrict__ b2,
    float* __restrict__ tmp, int cap, int ndiv)
{
  const int tid  = threadIdx.x;
  const int lane = tid & 63;
  const int sv   = lane & 7;          // sliver within row (8 int8 = 8 B)
  const int g    = lane >> 3;         // edge-group within wave (0..7)
  const int k    = blockIdx.x & 7;    // src-range == XCD (bid%8 round-robin)
  const int tblk = blockIdx.x >> 3;   // 0..255 within XCD
  const int wgid = tblk * 4 + (tid >> 6);   // 0..1023 within XCD
  const int r    = wgid >> 3;         // segment replica 0..127
  const int sub  = wgid & 7;          // sub-chunk 0..7

  float w2v[8];
  #pragma unroll
  for (int j = 0; j < 8; ++j) {
    const int pos = sv * 8 + j;
    const int ch  = (pos & 3) * 16 + (pos >> 2);
    w2v[j] = W2[ch];
  }
  const float b2v = b2[0];
  const int sd = sv * 2;              // dword offset of this lane's sliver
  const int sbase = k * ndiv;

  // Preload all 8 phase counts (removes the dependent load at phase entry)
  int cnts[8];
  #pragma unroll
  for (int j = 0; j < 8; ++j) cnts[j] = (int)cntT[(k * 8 + j) * NREP + r];

  #pragma unroll 1
  for (int j = 0; j < 8; ++j) {
    const int b = k * 8 + j;
    const int dbase = j * ndiv;
    const int cnt = cnts[j];
    const int chunk = (cnt + 7) >> 3;
    const int lo = sub * chunk;
    const int hi = (cnt < lo + chunk) ? cnt : lo + chunk;
    const unsigned int* sgp = seg + (size_t)(r * NBKT + b) * cap;
    float* tp = tmp + (size_t)(r * NBKT + b) * cap;

    int m = lo + g;
    if (m >= hi) continue;

    // Prologue: first entry's loads in flight.
    unsigned int v = sgp[m];
    int s_ = sbase + (int)(v & 0x7FFFu);
    int d_ = dbase + (int)(v >> 15);
    u32x2 pv = *(const u32x2*)(P8 + s_ * 16 + sd);
    u32x2 qv = *(const u32x2*)(Q8 + d_ * 16 + sd);
    float sp = SP[s_], sq = SQ[d_];

    while (true) {
      const int m2 = m + 8;
      const bool more = (m2 < hi);    // uniform within the 8-lane group
      u32x2 pv2, qv2; float sp2 = 0.f, sq2 = 0.f;
      if (more) {
        const unsigned int vn = sgp[m2];
        const int s2 = sbase + (int)(vn & 0x7FFFu);
        const int d2 = dbase + (int)(vn >> 15);
        pv2 = *(const u32x2*)(P8 + s2 * 16 + sd);
        qv2 = *(const u32x2*)(Q8 + d2 * 16 + sd);
        sp2 = SP[s2]; sq2 = SQ[d2];
      }

      float acc = dot8i(pv, qv, sp, sq, w2v);
      acc += __shfl_xor(acc, 1);
      acc += __shfl_xor(acc, 2);
      acc += __shfl_xor(acc, 4);
      if (sv == 0) tp[m] = acc + b2v;

      if (!more) break;
      m = m2; pv = pv2; qv = qv2; sp = sp2; sq = sq2;
    }
  }
}

// ---- pass 3: unscatter. Block (r = bid>>3, sub = bid&7) streams its slice
// of replica r's edge range in ORIGINAL order: posrec read + out write are
// coalesced; the tmp gather is confined to replica r's ~80 KB slice -> L2.
// posrec==0xFFFF (seg overflow, ~never): exact scalar recompute.
__global__ __launch_bounds__(256) void unscatter(
    const unsigned short* __restrict__ posrec, const float* __restrict__ tmp,
    float* __restrict__ out,
    const int* __restrict__ src, const int* __restrict__ dst,
    const unsigned int* __restrict__ P8, const unsigned int* __restrict__ Q8,
    const float* __restrict__ SP, const float* __restrict__ SQ,
    const float* __restrict__ W2, const float* __restrict__ b2,
    int E, int per, int cap)
{
  const int r   = blockIdx.x >> 3;
  const int sub = blockIdx.x & 7;
  const int lo_r = r * per;
  int lenr = E - lo_r;
  if (lenr <= 0) return;
  if (lenr > per) lenr = per;
  const int chunk = (lenr + 7) >> 3;
  const int lo = lo_r + sub * chunk;
  int hi = lo + chunk;
  const int end_r = lo_r + lenr;
  if (hi > end_r) hi = end_r;
  const float* tb = tmp + (size_t)r * NBKT * cap;

  for (int e = lo + threadIdx.x; e < hi; e += 256) {
    const unsigned int pr = posrec[e];
    if (pr != 0xFFFFu) {
      out[e] = tb[(pr >> 9) * cap + (pr & 511u)];
    } else {
      // exact recompute (statistically never taken)
      const int s_ = src[e], d_ = dst[e];
      const float sp = SP[s_], sq = SQ[d_];
      const float t_ = -128.f * (sp + sq);
      float acc = 0.f;
      for (int w = 0; w < 16; ++w) {
        const unsigned int pd = P8[(size_t)s_ * 16 + w];
        const unsigned int qd = Q8[(size_t)d_ * 16 + w];
        for (int bb = 0; bb < 4; ++bb) {
          const int pos = w * 4 + bb;
          const int ch  = (pos & 3) * 16 + (pos >> 2);
          float pf = (float)((pd >> (8 * bb)) & 0xffu);
          float qf = (float)((qd >> (8 * bb)) & 0xffu);
          float h = __builtin_fmaf(pf, sp, __builtin_fmaf(qf, sq, t_));
          h = fmaxf(h, 0.f);
          acc = __builtin_fmaf(h, W2[ch], acc);
        }
      }
      out[e] = acc + b2[0];
    }
  }
}

// ---- mid tier: R2 flat streamer (used when ws can't fit bucket lists) ----
__global__ __launch_bounds__(256) void edge_score(
    const unsigned int* __restrict__ P8, const unsigned int* __restrict__ Q8,
    const float* __restrict__ SP, const float* __restrict__ SQ,
    const int* __restrict__ src, const int* __restrict__ dst,
    const float* __restrict__ W2, const float* __restrict__ b2,
    float* __restrict__ out, int E)
{
  const int tid  = blockIdx.x * 256 + threadIdx.x;
  const int lane = threadIdx.x & 63;
  const int s    = lane & 7;
  const int g    = lane >> 3;
  const int wid  = tid >> 6;
  const int step = gridDim.x * 4 * 32;

  float w2v[8];
  #pragma unroll
  for (int j = 0; j < 8; ++j) {
    const int pos = s * 8 + j;
    const int ch  = (pos & 3) * 16 + (pos >> 2);
    w2v[j] = W2[ch];
  }
  const float b2v = b2[0];
  const int sd = s * 2;

  int e0 = wid * 32;
  if (e0 >= E) return;

  int iA, iB, iC, iD, jA, jB, jC, jD;
  {
    const int eA = e0 + g,      eAc = (eA < E) ? eA : E - 1;
    const int eB = e0 + 8 + g,  eBc = (eB < E) ? eB : E - 1;
    const int eC = e0 + 16 + g, eCc = (eC < E) ? eC : E - 1;
    const int eD = e0 + 24 + g, eDc = (eD < E) ? eD : E - 1;
    iA = src[eAc]; jA = dst[eAc];
    iB = src[eBc]; jB = dst[eBc];
    iC = src[eCc]; jC = dst[eCc];
    iD = src[eDc]; jD = dst[eDc];
  }
  float spA = SP[iA], sqA = SQ[jA];
  float spB = SP[iB], sqB = SQ[jB];
  float spC = SP[iC], sqC = SQ[jC];
  float spD = SP[iD], sqD = SQ[jD];

  while (true) {
    const u32x2 pA = *(const u32x2*)(P8 + iA * 16 + sd);
    const u32x2 qA = *(const u32x2*)(Q8 + jA * 16 + sd);
    const u32x2 pB = *(const u32x2*)(P8 + iB * 16 + sd);
    const u32x2 qB = *(const u32x2*)(Q8 + jB * 16 + sd);
    const u32x2 pC = *(const u32x2*)(P8 + iC * 16 + sd);
    const u32x2 qC = *(const u32x2*)(Q8 + jC * 16 + sd);
    const u32x2 pD = *(const u32x2*)(P8 + iD * 16 + sd);
    const u32x2 qD = *(const u32x2*)(Q8 + jD * 16 + sd);

    const int en = e0 + step;
    const bool more = (en < E);
    int nA = iA, nB = iB, nC = iC, nD = iD;
    int mA = jA, mB = jB, mC = jC, mD = jD;
    if (more) {
      const int fA = en + g,      fAc = (fA < E) ? fA : E - 1;
      const int fB = en + 8 + g,  fBc = (fB < E) ? fB : E - 1;
      const int fC = en + 16 + g, fCc = (fC < E) ? fC : E - 1;
      const int fD = en + 24 + g, fDc = (fD < E) ? fD : E - 1;
      nA = src[fAc]; mA = dst[fAc];
      nB = src[fBc]; mB = dst[fBc];
      nC = src[fCc]; mC = dst[fCc];
      nD = src[fDc]; mD = dst[fDc];
    }

    float accA = dot8i(pA, qA, spA, sqA, w2v);
    float accB = dot8i(pB, qB, spB, sqB, w2v);
    float accC = dot8i(pC, qC, spC, sqC, w2v);
    float accD = dot8i(pD, qD, spD, sqD, w2v);

    accA += __shfl_xor(accA, 1); accB += __shfl_xor(accB, 1);
    accC += __shfl_xor(accC, 1); accD += __shfl_xor(accD, 1);
    accA += __shfl_xor(accA, 2); accB += __shfl_xor(accB, 2);
    accC += __shfl_xor(accC, 2); accD += __shfl_xor(accD, 2);
    accA += __shfl_xor(accA, 4); accB += __shfl_xor(accB, 4);
    accC += __shfl_xor(accC, 4); accD += __shfl_xor(accD, 4);

    if (s == 0) {
      const int eA = e0 + g;
      const int eB = e0 + 8 + g;
      const int eC = e0 + 16 + g;
      const int eD = e0 + 24 + g;
      if (eA < E) out[eA] = accA + b2v;
      if (eB < E) out[eB] = accB + b2v;
      if (eC < E) out[eC] = accC + b2v;
      if (eD < E) out[eD] = accD + b2v;
    }

    if (!more) break;
    iA = nA; iB = nB; iC = nC; iD = nD;
    jA = mA; jB = mB; jC = mC; jD = mD;
    spA = SP[iA]; sqA = SQ[jA];
    spB = SP[iB]; sqB = SQ[jB];
    spC = SP[iC]; sqC = SQ[jC];
    spD = SP[iD]; sqD = SQ[jD];
    e0 = en;
  }
}

// ---- fallback: f32 gathers + MFMA (no workspace) ----
__global__ __launch_bounds__(256) void edge_mlp_f32(
    const float* __restrict__ nodes_emb, const int* __restrict__ src,
    const int* __restrict__ dst, const float* __restrict__ W1,
    const float* __restrict__ b1, const float* __restrict__ W2,
    const float* __restrict__ b2, float* __restrict__ out, int E)
{
  __shared__ unsigned short ls_w1t[64 * LDSTR];
  __shared__ float ls_b1[64];
  __shared__ float ls_w2[64];
  const int tid = threadIdx.x, wave = tid >> 6, lane = tid & 63;
  const int l15 = lane & 15, quad = lane >> 4;
  for (int i = tid; i < 64 * 128; i += 256) {
    int n = i >> 7, k = i & 127;
    ls_w1t[n * LDSTR + k] = f2bf_s(W1[k * 64 + n]);
  }
  if (tid < 64) { ls_b1[tid] = b1[tid]; ls_w2[tid] = W2[tid]; }
  __syncthreads();
  bf16x8 bfrag[4][4];
  #pragma unroll
  for (int tn = 0; tn < 4; ++tn)
    #pragma unroll
    for (int s = 0; s < 4; ++s)
      bfrag[tn][s] = *(const bf16x8*)&ls_w1t[(tn * 16 + l15) * LDSTR + s * 32 + quad * 8];
  float myb1[4], myw2[4];
  #pragma unroll
  for (int tn = 0; tn < 4; ++tn) { myb1[tn] = ls_b1[tn*16+l15]; myw2[tn] = ls_w2[tn*16+l15]; }
  const float b2v = b2[0];
  const int wave_base = blockIdx.x * (TPW * 64) + wave * (TPW * 16);
  #pragma unroll 1
  for (int t = 0; t < TPW; ++t) {
    const int tile_base = wave_base + t * 16;
    if (tile_base >= E) break;
    const int e = tile_base + l15;
    const int si = src[e], di = dst[e];
    const float* srow = nodes_emb + (long long)si * 64 + quad * 8;
    const float* drow = nodes_emb + (long long)di * 64 + quad * 8;
    float4 v0 = *(const float4*)(srow),      v1 = *(const float4*)(srow + 4);
    float4 v2 = *(const float4*)(srow + 32), v3 = *(const float4*)(srow + 36);
    float4 v4 = *(const float4*)(drow),      v5 = *(const float4*)(drow + 4);
    float4 v6 = *(const float4*)(drow + 32), v7 = *(const float4*)(drow + 36);
    bf16x8 afr[4] = {make_afrag(v0,v1), make_afrag(v2,v3), make_afrag(v4,v5), make_afrag(v6,v7)};
    f32x4 acc[4];
    #pragma unroll
    for (int tn = 0; tn < 4; ++tn) acc[tn] = (f32x4){0.f,0.f,0.f,0.f};
    #pragma unroll
    for (int s = 0; s < 4; ++s)
      #pragma unroll
      for (int tn = 0; tn < 4; ++tn)
        acc[tn] = __builtin_amdgcn_mfma_f32_16x16x32_bf16(afr[s], bfrag[tn][s], acc[tn], 0, 0, 0);
    #pragma unroll
    for (int r = 0; r < 4; ++r) {
      float p = 0.f;
      #pragma unroll
      for (int tn = 0; tn < 4; ++tn) {
        float h = fmaxf(acc[tn][r] + myb1[tn], 0.f);
        p = __builtin_fmaf(h, myw2[tn], p);
      }
      p += __shfl_xor(p, 1); p += __shfl_xor(p, 2);
      p += __shfl_xor(p, 4); p += __shfl_xor(p, 8);
      if (l15 == 0) out[tile_base + quad * 4 + r] = p + b2v;
    }
  }
}

extern "C" void kernel_launch(void* const* d_in, const int* in_sizes, int n_in,
                              void* d_out, int out_size, void* d_ws, size_t ws_size,
                              hipStream_t stream) {
  const float* nodes_emb = (const float*)d_in[0];
  const int*   src       = (const int*)d_in[1];
  const int*   dst       = (const int*)d_in[2];
  const float* W1        = (const float*)d_in[3];
  const float* b1        = (const float*)d_in[4];
  const float* W2        = (const float*)d_in[5];
  const float* b2        = (const float*)d_in[6];
  float* out = (float*)d_out;

  const int E = in_sizes[1];
  const int nodes_elems = in_sizes[0];               // N * 64
  const int N = nodes_elems / 64;
  const int ntiles = (N + 15) / 16;
  const int ndiv = (N + 7) / 8;                      // < 32768 required
  const int per  = (E + NREP - 1) / NREP;

  // cap: per-(replica,bucket) segment capacity, mean + 6 sigma + 8
  const long long cells = (long long)NBKT * NREP;
  const int perCell = (int)((E + cells - 1) / cells);
  const int sig = (int)ceilf(sqrtf((float)(perCell > 0 ? perCell : 1)));
  const int cap = perCell + 6 * sig + 8;

  // Workspace layout: P8 | Q8 | SP | SQ | cntT | posrec | seg | tmp
  const size_t szRow   = (size_t)N * 64;
  const size_t offSP   = szRow * 2;
  const size_t offSQ   = offSP + (size_t)N * 4;
  const size_t offCnt  = offSQ + (size_t)N * 4;
  const size_t offPos  = offCnt + (size_t)NBKT * NREP * 4;
  const size_t offSeg  = (offPos + (size_t)E * 2 + 7) & ~(size_t)7;
  const size_t offTmp  = offSeg + (size_t)NBKT * NREP * (size_t)cap * 4;
  const size_t need_full = offTmp + (size_t)NBKT * NREP * (size_t)cap * 4;
  const size_t need_mid  = offCnt;

  if (ws_size >= need_mid && N > 0) {
    unsigned int* P8 = (unsigned int*)d_ws;
    unsigned int* Q8 = (unsigned int*)((char*)d_ws + szRow);
    float* SP = (float*)((char*)d_ws + offSP);
    float* SQ = (float*)((char*)d_ws + offSQ);
    if (ws_size >= need_full && cap <= 511 && ndiv <= 32767) {
      unsigned int*   cntT   = (unsigned int*)((char*)d_ws + offCnt);
      unsigned short* posrec = (unsigned short*)((char*)d_ws + offPos);
      unsigned int*   seg    = (unsigned int*)((char*)d_ws + offSeg);
      float*          tmp    = (float*)((char*)d_ws + offTmp);
      hipLaunchKernelGGL(fused_prep, dim3(PROJ_BLOCKS + NREP), dim3(256), 0, stream,
                         nodes_emb, W1, b1, P8, Q8, SP, SQ,
                         src, dst, seg, posrec, cntT, N, ntiles, E, ndiv, cap);
      hipLaunchKernelGGL(edge_score_seg, dim3(2048), dim3(256), 0, stream,
                         P8, Q8, SP, SQ, seg, cntT, W2, b2, tmp, cap, ndiv);
      hipLaunchKernelGGL(unscatter, dim3(NREP * 8), dim3(256), 0, stream,
                         posrec, tmp, out, src, dst, P8, Q8, SP, SQ, W2, b2,
                         E, per, cap);
    } else {
      hipLaunchKernelGGL(node_proj, dim3(512), dim3(256), 0, stream,
                         nodes_emb, W1, b1, P8, Q8, SP, SQ, N, ntiles);
      hipLaunchKernelGGL(edge_score, dim3(4096), dim3(256), 0, stream,
                         P8, Q8, SP, SQ, src, dst, W2, b2, out, E);
    }
  } else {
    const int epb = TPW * 64;
    const int blocks = (E + epb - 1) / epb;
    hipLaunchKernelGGL(edge_mlp_f32, dim3(blocks), dim3(256), 0, stream,
                       nodes_emb, src, dst, W1, b1, W2, b2, out, E);
  }
}

// Round 6
// 195.017 us; speedup vs baseline: 1.0594x; 1.0594x over previous
//
#include <hip/hip_runtime.h>
#include <math.h>

// bf16 MFMA fragment types (gfx950): A/B = 8 bf16 (4 VGPR), C/D = 4 fp32
typedef __attribute__((ext_vector_type(8))) short bf16x8;
typedef __attribute__((ext_vector_type(4))) float f32x4;
typedef __attribute__((ext_vector_type(2))) unsigned int u32x2;
typedef __attribute__((ext_vector_type(4))) unsigned int u32x4;
typedef unsigned long long u64;

#define LDSTR 136            // W1^T LDS leading dim (shorts): 128 + 8 pad
#define TPW 8                // (fallback) 16-edge tiles per wave
#define NREP 128             // bucketize replicas
#define NBKT 64              // 8 src-ranges x 8 dst-ranges

// f32 -> bf16 round-to-nearest-even
static __device__ __forceinline__ unsigned int pack2bf(float x, float y) {
  unsigned int ux = __builtin_bit_cast(unsigned int, x);
  ux += 0x7fffu + ((ux >> 16) & 1u);
  unsigned int uy = __builtin_bit_cast(unsigned int, y);
  uy += 0x7fffu + ((uy >> 16) & 1u);
  return (ux >> 16) | (uy & 0xffff0000u);
}
static __device__ __forceinline__ unsigned short f2bf_s(float x) {
  unsigned int ux = __builtin_bit_cast(unsigned int, x);
  ux += 0x7fffu + ((ux >> 16) & 1u);
  return (unsigned short)(ux >> 16);
}
static __device__ __forceinline__ bf16x8 make_afrag(float4 lo, float4 hi) {
  u32x4 p;
  p[0] = pack2bf(lo.x, lo.y);
  p[1] = pack2bf(lo.z, lo.w);
  p[2] = pack2bf(hi.x, hi.y);
  p[3] = pack2bf(hi.z, hi.w);
  return __builtin_bit_cast(bf16x8, p);
}

// Quantize one f32 to biased uint8 given inv = 127/rowmax (0 if rowmax==0).
static __device__ __forceinline__ unsigned int q8(float v, float inv) {
  return (unsigned int)((int)rintf(v * inv) + 128);
}

// int8 edge MLP inner dot: h = relu((p-128)*sp + (q-128)*sq), acc += h*w2.
static __device__ __forceinline__ float dot8i(u32x2 P, u32x2 Q, float sp, float sq,
                                              const float* w2v) {
  const float t_ = -128.f * (sp + sq);
  float acc = 0.f;
  #pragma unroll
  for (int k2 = 0; k2 < 2; ++k2) {
    const unsigned int pd = P[k2], qd = Q[k2];
    #pragma unroll
    for (int b = 0; b < 4; ++b) {
      float pf = (float)((pd >> (8 * b)) & 0xffu);
      float qf = (float)((qd >> (8 * b)) & 0xffu);
      float h = __builtin_fmaf(pf, sp, __builtin_fmaf(qf, sq, t_));
      h = fmaxf(h, 0.f);
      acc = __builtin_fmaf(h, w2v[k2 * 4 + b], acc);
    }
  }
  return acc;
}

// ---- pass 0: per-node projections P = emb@W1[0:64], Q = emb@W1[64:128]+b1,
// INT8 rows (64 B) + per-row f32 scales. Permuted channel order
// ch(p) = (p&3)*16 + (p>>2). (R2 structure, proven absmax 0.0293)
__global__ __launch_bounds__(256) void node_proj(
    const float* __restrict__ emb, const float* __restrict__ W1,
    const float* __restrict__ b1,
    unsigned int* __restrict__ P8, unsigned int* __restrict__ Q8,
    float* __restrict__ SP, float* __restrict__ SQ, int N, int ntiles)
{
  __shared__ unsigned short ls_w1t[64 * LDSTR];   // W1^T [n][k]
  const int tid  = threadIdx.x;
  const int wave = tid >> 6;
  const int lane = tid & 63;
  const int l15  = lane & 15;
  const int quad = lane >> 4;

  for (int i = tid; i < 64 * 128; i += 256) {
    int k = i >> 6, n = i & 63;                    // W1[k][n], linear read
    ls_w1t[n * LDSTR + k] = f2bf_s(W1[i]);
  }
  __syncthreads();

  float b1q[4];
  #pragma unroll
  for (int tn = 0; tn < 4; ++tn) b1q[tn] = b1[tn * 16 + l15];

  bf16x8 bfragP[4][2], bfragQ[4][2];
  #pragma unroll
  for (int tn = 0; tn < 4; ++tn)
    #pragma unroll
    for (int s = 0; s < 2; ++s) {
      bfragP[tn][s] = *(const bf16x8*)&ls_w1t[(tn * 16 + l15) * LDSTR + s * 32 + quad * 8];
      bfragQ[tn][s] = *(const bf16x8*)&ls_w1t[(tn * 16 + l15) * LDSTR + 64 + s * 32 + quad * 8];
    }

  for (int tile = blockIdx.x * 4 + wave; tile < ntiles; tile += gridDim.x * 4) {
    const int base = tile * 16;

    bf16x8 afr0, afr1;
    {
      int node = base + l15;
      node = (node < N) ? node : N - 1;
      const float* rp = emb + (long long)node * 64 + quad * 8;
      afr0 = make_afrag(*(const float4*)(rp),      *(const float4*)(rp + 4));
      afr1 = make_afrag(*(const float4*)(rp + 32), *(const float4*)(rp + 36));
    }

    f32x4 aP[4], aQ[4];
    #pragma unroll
    for (int tn = 0; tn < 4; ++tn) { aP[tn] = (f32x4){0,0,0,0}; aQ[tn] = (f32x4){0,0,0,0}; }
    #pragma unroll
    for (int tn = 0; tn < 4; ++tn) {
      aP[tn] = __builtin_amdgcn_mfma_f32_16x16x32_bf16(afr0, bfragP[tn][0], aP[tn], 0, 0, 0);
      aQ[tn] = __builtin_amdgcn_mfma_f32_16x16x32_bf16(afr0, bfragQ[tn][0], aQ[tn], 0, 0, 0);
      aP[tn] = __builtin_amdgcn_mfma_f32_16x16x32_bf16(afr1, bfragP[tn][1], aP[tn], 0, 0, 0);
      aQ[tn] = __builtin_amdgcn_mfma_f32_16x16x32_bf16(afr1, bfragQ[tn][1], aQ[tn], 0, 0, 0);
    }

    #pragma unroll
    for (int r = 0; r < 4; ++r) {
      const int m = base + quad * 4 + r;
      float vp0 = aP[0][r], vp1 = aP[1][r], vp2 = aP[2][r], vp3 = aP[3][r];
      float vq0 = aQ[0][r] + b1q[0], vq1 = aQ[1][r] + b1q[1];
      float vq2 = aQ[2][r] + b1q[2], vq3 = aQ[3][r] + b1q[3];

      float mp = fmaxf(fmaxf(fabsf(vp0), fabsf(vp1)), fmaxf(fabsf(vp2), fabsf(vp3)));
      float mq = fmaxf(fmaxf(fabsf(vq0), fabsf(vq1)), fmaxf(fabsf(vq2), fabsf(vq3)));
      mp = fmaxf(mp, __shfl_xor(mp, 1)); mq = fmaxf(mq, __shfl_xor(mq, 1));
      mp = fmaxf(mp, __shfl_xor(mp, 2)); mq = fmaxf(mq, __shfl_xor(mq, 2));
      mp = fmaxf(mp, __shfl_xor(mp, 4)); mq = fmaxf(mq, __shfl_xor(mq, 4));
      mp = fmaxf(mp, __shfl_xor(mp, 8)); mq = fmaxf(mq, __shfl_xor(mq, 8));

      const float invP = (mp > 0.f) ? 127.f / mp : 0.f;
      const float invQ = (mq > 0.f) ? 127.f / mq : 0.f;

      if (m < N) {
        unsigned int pw = q8(vp0, invP) | (q8(vp1, invP) << 8) |
                          (q8(vp2, invP) << 16) | (q8(vp3, invP) << 24);
        unsigned int qw = q8(vq0, invQ) | (q8(vq1, invQ) << 8) |
                          (q8(vq2, invQ) << 16) | (q8(vq3, invQ) << 24);
        P8[(long long)m * 16 + l15] = pw;
        Q8[(long long)m * 16 + l15] = qw;
        if (l15 == 0) {
          SP[m] = mp * (1.f / 127.f);
          SQ[m] = mq * (1.f / 127.f);
        }
      }
    }
  }
}

// ---- pass 1: bucketize, ILP-4. Replica r bins its contiguous edge range
// into 64 (src-range, dst-range) segments. 4 edges per thread per
// super-iteration: 8 index loads issued together (independent chains),
// then 4x (div / LDS-atomic / store). Dependent iterations per block: 16
// (was 61). 4-B seg entries (s%ndiv | (d%ndiv)<<15); posrec[e]=(bkt<<9|pos).
__global__ __launch_bounds__(256) void bucketize(
    const int* __restrict__ src, const int* __restrict__ dst,
    unsigned int* __restrict__ seg, unsigned short* __restrict__ posrec,
    unsigned int* __restrict__ cntT, int E, int ndiv, int cap)
{
  __shared__ unsigned int curs[NBKT];
  const int r = blockIdx.x;
  const int per = (E + NREP - 1) / NREP;
  const int lo = r * per;
  const int hi = (lo + per < E) ? lo + per : E;
  for (int i = threadIdx.x; i < NBKT; i += 256) curs[i] = 0;
  __syncthreads();

  for (int e0 = lo + threadIdx.x; e0 < hi; e0 += 1024) {
    const int e1 = e0 + 256, e2 = e0 + 512, e3 = e0 + 768;
    const int e1c = (e1 < hi) ? e1 : hi - 1;
    const int e2c = (e2 < hi) ? e2 : hi - 1;
    const int e3c = (e3 < hi) ? e3 : hi - 1;
    // 8 independent loads in flight
    const int s0 = src[e0],  d0 = dst[e0];
    const int s1 = src[e1c], d1 = dst[e1c];
    const int s2 = src[e2c], d2 = dst[e2c];
    const int s3 = src[e3c], d3 = dst[e3c];

#define BK_PROC(EE, SS, DD)                                                   \
    {                                                                         \
      const int bi = (SS) / ndiv, bj = (DD) / ndiv;                           \
      const int bkt = bi * 8 + bj;                                            \
      const unsigned int pos = atomicAdd(&curs[bkt], 1u);                     \
      unsigned short pr = 0xFFFFu;                                            \
      if (pos < (unsigned)cap) {                                              \
        seg[((size_t)(r * NBKT + bkt)) * cap + pos] =                         \
            (unsigned)((SS) - bi * ndiv) | ((unsigned)((DD) - bj * ndiv) << 15); \
        pr = (unsigned short)(((unsigned)bkt << 9) | pos);                    \
      }                                                                       \
      posrec[EE] = pr;                                                        \
    }

    BK_PROC(e0, s0, d0);
    if (e1 < hi) BK_PROC(e1, s1, d1);
    if (e2 < hi) BK_PROC(e2, s2, d2);
    if (e3 < hi) BK_PROC(e3, s3, d3);
#undef BK_PROC
  }
  __syncthreads();
  for (int bkt = threadIdx.x; bkt < NBKT; bkt += 256) {
    unsigned int c = curs[bkt];
    cntT[bkt * NREP + r] = (c < (unsigned)cap) ? c : (unsigned)cap;
  }
}

// ---- pass 2: bucketed edge scorer, zero-sync work assignment + ILP-4.
// XCD k (bid%8): wave w of 1024 owns (segment r=w>>3, sub-chunk w&7), walks
// phases j=0..7 (bucket b=k*8+j). Per super-iteration each 8-lane group
// processes 4 edges: 4 seg reads -> 8 row-gathers + 8 scale loads (all
// independent, in flight together) -> 4 dots. Compact writes to tmp.
__global__ __launch_bounds__(256) void edge_score_seg(
    const unsigned int* __restrict__ P8, const unsigned int* __restrict__ Q8,
    const float* __restrict__ SP, const float* __restrict__ SQ,
    const unsigned int* __restrict__ seg, const unsigned int* __restrict__ cntT,
    const float* __restrict__ W2, const float* __restrict__ b2,
    float* __restrict__ tmp, int cap, int ndiv)
{
  const int tid  = threadIdx.x;
  const int lane = tid & 63;
  const int sv   = lane & 7;          // sliver within row (8 int8 = 8 B)
  const int g    = lane >> 3;         // edge-group within wave (0..7)
  const int k    = blockIdx.x & 7;    // src-range == XCD (bid%8 round-robin)
  const int tblk = blockIdx.x >> 3;   // 0..255 within XCD
  const int wgid = tblk * 4 + (tid >> 6);   // 0..1023 within XCD
  const int r    = wgid >> 3;         // segment replica 0..127
  const int sub  = wgid & 7;          // sub-chunk 0..7

  float w2v[8];
  #pragma unroll
  for (int j = 0; j < 8; ++j) {
    const int pos = sv * 8 + j;
    const int ch  = (pos & 3) * 16 + (pos >> 2);
    w2v[j] = W2[ch];
  }
  const float b2v = b2[0];
  const int sd = sv * 2;              // dword offset of this lane's sliver
  const int sbase = k * ndiv;

  // Preload all 8 phase counts (no dependent load at phase entry)
  int cnts[8];
  #pragma unroll
  for (int j = 0; j < 8; ++j) cnts[j] = (int)cntT[(k * 8 + j) * NREP + r];

  #pragma unroll 1
  for (int j = 0; j < 8; ++j) {
    const int b = k * 8 + j;
    const int dbase = j * ndiv;
    const int cnt = cnts[j];
    const int chunk = (cnt + 7) >> 3;
    const int lo = sub * chunk;
    const int hi = (cnt < lo + chunk) ? cnt : lo + chunk;
    if (lo >= hi) continue;
    const unsigned int* sgp = seg + (size_t)(r * NBKT + b) * cap;
    float* tp = tmp + (size_t)(r * NBKT + b) * cap;

    #pragma unroll 1
    for (int m0 = lo; m0 < hi; m0 += 32) {
      const int mA = m0 + g;
      const int mB = m0 + 8 + g;
      const int mC = m0 + 16 + g;
      const int mD = m0 + 24 + g;
      const int mAc = (mA < hi) ? mA : hi - 1;
      const int mBc = (mB < hi) ? mB : hi - 1;
      const int mCc = (mC < hi) ? mC : hi - 1;
      const int mDc = (mD < hi) ? mD : hi - 1;

      // 4 seg reads in flight
      const unsigned int vA = sgp[mAc];
      const unsigned int vB = sgp[mBc];
      const unsigned int vC = sgp[mCc];
      const unsigned int vD = sgp[mDc];

      const int sA = sbase + (int)(vA & 0x7FFFu), dA = dbase + (int)(vA >> 15);
      const int sB = sbase + (int)(vB & 0x7FFFu), dB = dbase + (int)(vB >> 15);
      const int sC = sbase + (int)(vC & 0x7FFFu), dC = dbase + (int)(vC >> 15);
      const int sD = sbase + (int)(vD & 0x7FFFu), dD = dbase + (int)(vD >> 15);

      // 8 row-gathers + 8 scale loads, all independent
      const u32x2 pA = *(const u32x2*)(P8 + sA * 16 + sd);
      const u32x2 qA = *(const u32x2*)(Q8 + dA * 16 + sd);
      const u32x2 pB = *(const u32x2*)(P8 + sB * 16 + sd);
      const u32x2 qB = *(const u32x2*)(Q8 + dB * 16 + sd);
      const u32x2 pC = *(const u32x2*)(P8 + sC * 16 + sd);
      const u32x2 qC = *(const u32x2*)(Q8 + dC * 16 + sd);
      const u32x2 pD = *(const u32x2*)(P8 + sD * 16 + sd);
      const u32x2 qD = *(const u32x2*)(Q8 + dD * 16 + sd);
      const float spA = SP[sA], sqA = SQ[dA];
      const float spB = SP[sB], sqB = SQ[dB];
      const float spC = SP[sC], sqC = SQ[dC];
      const float spD = SP[sD], sqD = SQ[dD];

      float accA = dot8i(pA, qA, spA, sqA, w2v);
      float accB = dot8i(pB, qB, spB, sqB, w2v);
      float accC = dot8i(pC, qC, spC, sqC, w2v);
      float accD = dot8i(pD, qD, spD, sqD, w2v);

      accA += __shfl_xor(accA, 1); accB += __shfl_xor(accB, 1);
      accC += __shfl_xor(accC, 1); accD += __shfl_xor(accD, 1);
      accA += __shfl_xor(accA, 2); accB += __shfl_xor(accB, 2);
      accC += __shfl_xor(accC, 2); accD += __shfl_xor(accD, 2);
      accA += __shfl_xor(accA, 4); accB += __shfl_xor(accB, 4);
      accC += __shfl_xor(accC, 4); accD += __shfl_xor(accD, 4);

      if (sv == 0) {
        if (mA < hi) tp[mA] = accA + b2v;
        if (mB < hi) tp[mB] = accB + b2v;
        if (mC < hi) tp[mC] = accC + b2v;
        if (mD < hi) tp[mD] = accD + b2v;
      }
    }
  }
}

// ---- pass 3: unscatter. Block (r = bid>>3, sub = bid&7) streams its slice
// of replica r's edge range in ORIGINAL order: posrec read + out write are
// coalesced; the tmp gather is confined to replica r's ~90 KB slice -> L2.
// posrec==0xFFFF (seg overflow, ~never): exact scalar recompute.
__global__ __launch_bounds__(256) void unscatter(
    const unsigned short* __restrict__ posrec, const float* __restrict__ tmp,
    float* __restrict__ out,
    const int* __restrict__ src, const int* __restrict__ dst,
    const unsigned int* __restrict__ P8, const unsigned int* __restrict__ Q8,
    const float* __restrict__ SP, const float* __restrict__ SQ,
    const float* __restrict__ W2, const float* __restrict__ b2,
    int E, int per, int cap)
{
  const int r   = blockIdx.x >> 3;
  const int sub = blockIdx.x & 7;
  const int lo_r = r * per;
  int lenr = E - lo_r;
  if (lenr <= 0) return;
  if (lenr > per) lenr = per;
  const int chunk = (lenr + 7) >> 3;
  const int lo = lo_r + sub * chunk;
  int hi = lo + chunk;
  const int end_r = lo_r + lenr;
  if (hi > end_r) hi = end_r;
  const float* tb = tmp + (size_t)r * NBKT * cap;

  for (int e = lo + threadIdx.x; e < hi; e += 256) {
    const unsigned int pr = posrec[e];
    if (pr != 0xFFFFu) {
      out[e] = tb[(pr >> 9) * cap + (pr & 511u)];
    } else {
      // exact recompute (statistically never taken)
      const int s_ = src[e], d_ = dst[e];
      const float sp = SP[s_], sq = SQ[d_];
      const float t_ = -128.f * (sp + sq);
      float acc = 0.f;
      for (int w = 0; w < 16; ++w) {
        const unsigned int pd = P8[(size_t)s_ * 16 + w];
        const unsigned int qd = Q8[(size_t)d_ * 16 + w];
        for (int bb = 0; bb < 4; ++bb) {
          const int pos = w * 4 + bb;
          const int ch  = (pos & 3) * 16 + (pos >> 2);
          float pf = (float)((pd >> (8 * bb)) & 0xffu);
          float qf = (float)((qd >> (8 * bb)) & 0xffu);
          float h = __builtin_fmaf(pf, sp, __builtin_fmaf(qf, sq, t_));
          h = fmaxf(h, 0.f);
          acc = __builtin_fmaf(h, W2[ch], acc);
        }
      }
      out[e] = acc + b2[0];
    }
  }
}

// ---- mid tier: R2 flat streamer (used when ws can't fit bucket lists) ----
__global__ __launch_bounds__(256) void edge_score(
    const unsigned int* __restrict__ P8, const unsigned int* __restrict__ Q8,
    const float* __restrict__ SP, const float* __restrict__ SQ,
    const int* __restrict__ src, const int* __restrict__ dst,
    const float* __restrict__ W2, const float* __restrict__ b2,
    float* __restrict__ out, int E)
{
  const int tid  = blockIdx.x * 256 + threadIdx.x;
  const int lane = threadIdx.x & 63;
  const int s    = lane & 7;
  const int g    = lane >> 3;
  const int wid  = tid >> 6;
  const int step = gridDim.x * 4 * 32;

  float w2v[8];
  #pragma unroll
  for (int j = 0; j < 8; ++j) {
    const int pos = s * 8 + j;
    const int ch  = (pos & 3) * 16 + (pos >> 2);
    w2v[j] = W2[ch];
  }
  const float b2v = b2[0];
  const int sd = s * 2;

  int e0 = wid * 32;
  if (e0 >= E) return;

  int iA, iB, iC, iD, jA, jB, jC, jD;
  {
    const int eA = e0 + g,      eAc = (eA < E) ? eA : E - 1;
    const int eB = e0 + 8 + g,  eBc = (eB < E) ? eB : E - 1;
    const int eC = e0 + 16 + g, eCc = (eC < E) ? eC : E - 1;
    const int eD = e0 + 24 + g, eDc = (eD < E) ? eD : E - 1;
    iA = src[eAc]; jA = dst[eAc];
    iB = src[eBc]; jB = dst[eBc];
    iC = src[eCc]; jC = dst[eCc];
    iD = src[eDc]; jD = dst[eDc];
  }
  float spA = SP[iA], sqA = SQ[jA];
  float spB = SP[iB], sqB = SQ[jB];
  float spC = SP[iC], sqC = SQ[jC];
  float spD = SP[iD], sqD = SQ[jD];

  while (true) {
    const u32x2 pA = *(const u32x2*)(P8 + iA * 16 + sd);
    const u32x2 qA = *(const u32x2*)(Q8 + jA * 16 + sd);
    const u32x2 pB = *(const u32x2*)(P8 + iB * 16 + sd);
    const u32x2 qB = *(const u32x2*)(Q8 + jB * 16 + sd);
    const u32x2 pC = *(const u32x2*)(P8 + iC * 16 + sd);
    const u32x2 qC = *(const u32x2*)(Q8 + jC * 16 + sd);
    const u32x2 pD = *(const u32x2*)(P8 + iD * 16 + sd);
    const u32x2 qD = *(const u32x2*)(Q8 + jD * 16 + sd);

    const int en = e0 + step;
    const bool more = (en < E);
    int nA = iA, nB = iB, nC = iC, nD = iD;
    int mA = jA, mB = jB, mC = jC, mD = jD;
    if (more) {
      const int fA = en + g,      fAc = (fA < E) ? fA : E - 1;
      const int fB = en + 8 + g,  fBc = (fB < E) ? fB : E - 1;
      const int fC = en + 16 + g, fCc = (fC < E) ? fC : E - 1;
      const int fD = en + 24 + g, fDc = (fD < E) ? fD : E - 1;
      nA = src[fAc]; mA = dst[fAc];
      nB = src[fBc]; mB = dst[fBc];
      nC = src[fCc]; mC = dst[fCc];
      nD = src[fDc]; mD = dst[fDc];
    }

    float accA = dot8i(pA, qA, spA, sqA, w2v);
    float accB = dot8i(pB, qB, spB, sqB, w2v);
    float accC = dot8i(pC, qC, spC, sqC, w2v);
    float accD = dot8i(pD, qD, spD, sqD, w2v);

    accA += __shfl_xor(accA, 1); accB += __shfl_xor(accB, 1);
    accC += __shfl_xor(accC, 1); accD += __shfl_xor(accD, 1);
    accA += __shfl_xor(accA, 2); accB += __shfl_xor(accB, 2);
    accC += __shfl_xor(accC, 2); accD += __shfl_xor(accD, 2);
    accA += __shfl_xor(accA, 4); accB += __shfl_xor(accB, 4);
    accC += __shfl_xor(accC, 4); accD += __shfl_xor(accD, 4);

    if (s == 0) {
      const int eA = e0 + g;
      const int eB = e0 + 8 + g;
      const int eC = e0 + 16 + g;
      const int eD = e0 + 24 + g;
      if (eA < E) out[eA] = accA + b2v;
      if (eB < E) out[eB] = accB + b2v;
      if (eC < E) out[eC] = accC + b2v;
      if (eD < E) out[eD] = accD + b2v;
    }

    if (!more) break;
    iA = nA; iB = nB; iC = nC; iD = nD;
    jA = mA; jB = mB; jC = mC; jD = mD;
    spA = SP[iA]; sqA = SQ[jA];
    spB = SP[iB]; sqB = SQ[jB];
    spC = SP[iC]; sqC = SQ[jC];
    spD = SP[iD]; sqD = SQ[jD];
    e0 = en;
  }
}

// ---- fallback: f32 gathers + MFMA (no workspace) ----
__global__ __launch_bounds__(256) void edge_mlp_f32(
    const float* __restrict__ nodes_emb, const int* __restrict__ src,
    const int* __restrict__ dst, const float* __restrict__ W1,
    const float* __restrict__ b1, const float* __restrict__ W2,
    const float* __restrict__ b2, float* __restrict__ out, int E)
{
  __shared__ unsigned short ls_w1t[64 * LDSTR];
  __shared__ float ls_b1[64];
  __shared__ float ls_w2[64];
  const int tid = threadIdx.x, wave = tid >> 6, lane = tid & 63;
  const int l15 = lane & 15, quad = lane >> 4;
  for (int i = tid; i < 64 * 128; i += 256) {
    int n = i >> 7, k = i & 127;
    ls_w1t[n * LDSTR + k] = f2bf_s(W1[k * 64 + n]);
  }
  if (tid < 64) { ls_b1[tid] = b1[tid]; ls_w2[tid] = W2[tid]; }
  __syncthreads();
  bf16x8 bfrag[4][4];
  #pragma unroll
  for (int tn = 0; tn < 4; ++tn)
    #pragma unroll
    for (int s = 0; s < 4; ++s)
      bfrag[tn][s] = *(const bf16x8*)&ls_w1t[(tn * 16 + l15) * LDSTR + s * 32 + quad * 8];
  float myb1[4], myw2[4];
  #pragma unroll
  for (int tn = 0; tn < 4; ++tn) { myb1[tn] = ls_b1[tn*16+l15]; myw2[tn] = ls_w2[tn*16+l15]; }
  const float b2v = b2[0];
  const int wave_base = blockIdx.x * (TPW * 64) + wave * (TPW * 16);
  #pragma unroll 1
  for (int t = 0; t < TPW; ++t) {
    const int tile_base = wave_base + t * 16;
    if (tile_base >= E) break;
    const int e = tile_base + l15;
    const int si = src[e], di = dst[e];
    const float* srow = nodes_emb + (long long)si * 64 + quad * 8;
    const float* drow = nodes_emb + (long long)di * 64 + quad * 8;
    float4 v0 = *(const float4*)(srow),      v1 = *(const float4*)(srow + 4);
    float4 v2 = *(const float4*)(srow + 32), v3 = *(const float4*)(srow + 36);
    float4 v4 = *(const float4*)(drow),      v5 = *(const float4*)(drow + 4);
    float4 v6 = *(const float4*)(drow + 32), v7 = *(const float4*)(drow + 36);
    bf16x8 afr[4] = {make_afrag(v0,v1), make_afrag(v2,v3), make_afrag(v4,v5), make_afrag(v6,v7)};
    f32x4 acc[4];
    #pragma unroll
    for (int tn = 0; tn < 4; ++tn) acc[tn] = (f32x4){0.f,0.f,0.f,0.f};
    #pragma unroll
    for (int s = 0; s < 4; ++s)
      #pragma unroll
      for (int tn = 0; tn < 4; ++tn)
        acc[tn] = __builtin_amdgcn_mfma_f32_16x16x32_bf16(afr[s], bfrag[tn][s], acc[tn], 0, 0, 0);
    #pragma unroll
    for (int r = 0; r < 4; ++r) {
      float p = 0.f;
      #pragma unroll
      for (int tn = 0; tn < 4; ++tn) {
        float h = fmaxf(acc[tn][r] + myb1[tn], 0.f);
        p = __builtin_fmaf(h, myw2[tn], p);
      }
      p += __shfl_xor(p, 1); p += __shfl_xor(p, 2);
      p += __shfl_xor(p, 4); p += __shfl_xor(p, 8);
      if (l15 == 0) out[tile_base + quad * 4 + r] = p + b2v;
    }
  }
}

extern "C" void kernel_launch(void* const* d_in, const int* in_sizes, int n_in,
                              void* d_out, int out_size, void* d_ws, size_t ws_size,
                              hipStream_t stream) {
  const float* nodes_emb = (const float*)d_in[0];
  const int*   src       = (const int*)d_in[1];
  const int*   dst       = (const int*)d_in[2];
  const float* W1        = (const float*)d_in[3];
  const float* b1        = (const float*)d_in[4];
  const float* W2        = (const float*)d_in[5];
  const float* b2        = (const float*)d_in[6];
  float* out = (float*)d_out;

  const int E = in_sizes[1];
  const int nodes_elems = in_sizes[0];               // N * 64
  const int N = nodes_elems / 64;
  const int ntiles = (N + 15) / 16;
  const int ndiv = (N + 7) / 8;                      // < 32768 required
  const int per  = (E + NREP - 1) / NREP;

  // cap: per-(replica,bucket) segment capacity, mean + 6 sigma + 8
  const long long cells = (long long)NBKT * NREP;
  const int perCell = (int)((E + cells - 1) / cells);
  const int sig = (int)ceilf(sqrtf((float)(perCell > 0 ? perCell : 1)));
  const int cap = perCell + 6 * sig + 8;

  // Workspace layout: P8 | Q8 | SP | SQ | cntT | posrec | seg | tmp
  const size_t szRow   = (size_t)N * 64;
  const size_t offSP   = szRow * 2;
  const size_t offSQ   = offSP + (size_t)N * 4;
  const size_t offCnt  = offSQ + (size_t)N * 4;
  const size_t offPos  = offCnt + (size_t)NBKT * NREP * 4;
  const size_t offSeg  = (offPos + (size_t)E * 2 + 7) & ~(size_t)7;
  const size_t offTmp  = offSeg + (size_t)NBKT * NREP * (size_t)cap * 4;
  const size_t need_full = offTmp + (size_t)NBKT * NREP * (size_t)cap * 4;
  const size_t need_mid  = offCnt;

  if (ws_size >= need_mid && N > 0) {
    unsigned int* P8 = (unsigned int*)d_ws;
    unsigned int* Q8 = (unsigned int*)((char*)d_ws + szRow);
    float* SP = (float*)((char*)d_ws + offSP);
    float* SQ = (float*)((char*)d_ws + offSQ);
    hipLaunchKernelGGL(node_proj, dim3(512), dim3(256), 0, stream,
                       nodes_emb, W1, b1, P8, Q8, SP, SQ, N, ntiles);
    if (ws_size >= need_full && cap <= 511 && ndiv <= 32767) {
      unsigned int*   cntT   = (unsigned int*)((char*)d_ws + offCnt);
      unsigned short* posrec = (unsigned short*)((char*)d_ws + offPos);
      unsigned int*   seg    = (unsigned int*)((char*)d_ws + offSeg);
      float*          tmp    = (float*)((char*)d_ws + offTmp);
      hipLaunchKernelGGL(bucketize, dim3(NREP), dim3(256), 0, stream,
                         src, dst, seg, posrec, cntT, E, ndiv, cap);
      hipLaunchKernelGGL(edge_score_seg, dim3(2048), dim3(256), 0, stream,
                         P8, Q8, SP, SQ, seg, cntT, W2, b2, tmp, cap, ndiv);
      hipLaunchKernelGGL(unscatter, dim3(NREP * 8), dim3(256), 0, stream,
                         posrec, tmp, out, src, dst, P8, Q8, SP, SQ, W2, b2,
                         E, per, cap);
    } else {
      hipLaunchKernelGGL(edge_score, dim3(4096), dim3(256), 0, stream,
                         P8, Q8, SP, SQ, src, dst, W2, b2, out, E);
    }
  } else {
    const int epb = TPW * 64;
    const int blocks = (E + epb - 1) / epb;
    hipLaunchKernelGGL(edge_mlp_f32, dim3(blocks), dim3(256), 0, stream,
                       nodes_emb, src, dst, W1, b1, W2, b2, out, E);
  }
}